// Round 7
// baseline (181.827 us; speedup 1.0000x reference)
//
#include <hip/hip_runtime.h>
#include <hip/hip_bf16.h>

// MultiScaleRoIAlign (torchvision semantics, aligned=False), MI355X.
// Inputs: feat0..feat3 fp32 [2,256,H,H] H={200,100,50,25}, boxes fp32 [2,256,4]
// Output: fp32 [512, 256, 7, 7]
// Strategy: channels-last FP16 copy of all levels in d_ws, then 16B/8-channel
// vector gathers. This round: half-size fp32 LDS tile (128ch x 64sp) in the
// transpose for 4 blocks/CU occupancy (R3 showed 66KB tile -> 16% occupancy).

#define IMGC   256
#define OUTP   7
#define NBIN   49
#define SAMP   14
#define BT     128     // threads per roialign block
#define SLD    65      // transpose LDS leading dim (floats)
#define TLD    132     // roialign tile leading dim (floats)

// ws layout (fp16 element offsets), channels-last [B,H,W,C] per level
#define WS_O1 20480000
#define WS_O2 25600000
#define WS_O3 26880000
#define WS_TOT 27200000

typedef _Float16 half2v __attribute__((ext_vector_type(2)));
typedef _Float16 half8  __attribute__((ext_vector_type(8)));

// ---------------------------------------------------------------------------
// Transpose [2,256,H,W] fp32 -> [2,H,W,256] fp16, all 4 levels fused.
// Block = 128 channels x 64 spatial, fp32 LDS tile 33,280 B -> 4 blocks/CU.
// Blocks: lvl0 625*2*2=2500, lvl1 157*2*2=628, lvl2 160, lvl3 40 -> 3328
// ---------------------------------------------------------------------------
__global__ __launch_bounds__(256) void transpose_cl_h3_kernel(
    const float* __restrict__ f0, const float* __restrict__ f1,
    const float* __restrict__ f2, const float* __restrict__ f3,
    _Float16* __restrict__ ws)
{
    __shared__ float t[128 * SLD];   // 33,280 B

    int bx = blockIdx.x;
    int lvl, r;
    if (bx < 2500)      { lvl = 0; r = bx; }
    else if (bx < 3128) { lvl = 1; r = bx - 2500; }
    else if (bx < 3288) { lvl = 2; r = bx - 3128; }
    else                { lvl = 3; r = bx - 3288; }

    const int Mtab[4]  = {40000, 10000, 2500, 625};
    const int Mttab[4] = {625, 157, 40, 10};
    const int wsoff[4] = {0, WS_O1, WS_O2, WS_O3};

    const float* in = (lvl == 0) ? f0 : (lvl == 1) ? f1 : (lvl == 2) ? f2 : f3;
    _Float16* outp = ws + wsoff[lvl];
    const int M  = Mtab[lvl];
    const int Mt = Mttab[lvl];

    int mt   = r % Mt;
    int rest = r / Mt;
    int cg   = rest & 1;      // 128-channel group
    int bb   = rest >> 1;     // batch
    int m0   = mt * 64;

    const int tid = threadIdx.x;
    const int tx  = tid & 63;    // spatial within tile (lane)
    const int tg  = tid >> 6;    // wave id: 32 channels each

    // ---- read phase: 256B/instr coalesced; LDS writes bank=lane%32 (free) ----
    {
        int m = m0 + tx;
        if (m < M) {
            const float* base = in + (size_t)(bb * IMGC + cg * 128 + tg * 32) * M + m;
            #pragma unroll
            for (int k = 0; k < 32; ++k)
                t[(tg * 32 + k) * SLD + tx] = base[(size_t)k * M];
        }
    }
    __syncthreads();

    // ---- write-out: 256B/wave contiguous fp16 ----
    #pragma unroll
    for (int k = 0; k < 16; ++k) {
        int idx = tid + 256 * k;     // 0..4095 = mm*64 + cpair
        int mm  = idx >> 6;
        int cp  = idx & 63;
        int m2  = m0 + mm;
        if (m2 < M) {
            half2v h;
            h.x = (_Float16)t[(2 * cp) * SLD + mm];
            h.y = (_Float16)t[(2 * cp + 1) * SLD + mm];
            *(half2v*)&outp[(size_t)(bb * M + m2) * IMGC + cg * 128 + 2 * cp] = h;
        }
    }
}

// ---------------------------------------------------------------------------
// RoIAlign from channels-last fp16 (verbatim R3 version — HW-proven).
// Block = (roi, 128-channel chunk); thread = (octet o=tid&15, bin-group tid>>4).
// Each tap = one 16B half8 load covering 8 channels.
// ---------------------------------------------------------------------------
__global__ __launch_bounds__(BT) void roialign_h_kernel(
    const _Float16* __restrict__ ws, const float* __restrict__ boxes,
    float* __restrict__ out)
{
    __shared__ float  s_ly[SAMP], s_wy[SAMP], s_lx[SAMP], s_wx[SAMP];
    __shared__ int    s_yol[SAMP], s_yoh[SAMP], s_xol[SAMP], s_xoh[SAMP];
    __shared__ float4 s_w[SAMP * SAMP];
    __shared__ float  tile[NBIN * TLD];

    const int tid = threadIdx.x;
    const int blk = blockIdx.x;
    const int n   = blk >> 1;
    const int c0  = (blk & 1) * BT;
    const int b   = n >> 8;

    const float x1 = boxes[n * 4 + 0];
    const float y1 = boxes[n * 4 + 1];
    const float x2 = boxes[n * 4 + 2];
    const float y2 = boxes[n * 4 + 3];

    float s = sqrtf(fmaxf((x2 - x1) * (y2 - y1), 1e-12f));
    float lf = floorf(4.0f + log2f(s / 224.0f) + 1e-6f);
    int lvl = (int)fminf(fmaxf(lf, 2.0f), 5.0f) - 2;

    const int   Htab[4]   = {200, 100, 50, 25};
    const float sctab[4]  = {0.25f, 0.125f, 0.0625f, 0.03125f};
    const int   wsoff[4]  = {0, WS_O1, WS_O2, WS_O3};
    const int   H = Htab[lvl];
    const int   W = H;
    const float scale = sctab[lvl];
    const _Float16* fp = ws + wsoff[lvl];

    const float x1s = x1 * scale, y1s = y1 * scale;
    const float roi_w = fmaxf(x2 * scale - x1s, 1.0f);
    const float roi_h = fmaxf(y2 * scale - y1s, 1.0f);
    const float bin_w = roi_w * (1.0f / OUTP);
    const float bin_h = roi_h * (1.0f / OUTP);

    // ---- descriptors (offsets in half8 units) ----
    if (tid < SAMP) {
        int t = tid;
        float off = (float)(t >> 1) + 0.25f + 0.5f * (float)(t & 1);
        float y = y1s + off * bin_h;
        float v = (y > -1.0f && y < (float)H) ? 1.0f : 0.0f;
        y = fmaxf(y, 0.0f);
        int yl = min((int)y, H - 1);
        int yh = min(yl + 1, H - 1);
        if (yl >= H - 1) y = (float)yl;
        s_ly[t] = y - (float)yl;
        s_wy[t] = v;
        s_yol[t] = ((b * H + yl) * W) * (IMGC / 8);
        s_yoh[t] = ((b * H + yh) * W) * (IMGC / 8);
    } else if (tid >= 64 && tid < 64 + SAMP) {
        int t = tid - 64;
        float off = (float)(t >> 1) + 0.25f + 0.5f * (float)(t & 1);
        float x = x1s + off * bin_w;
        float v = (x > -1.0f && x < (float)W) ? 1.0f : 0.0f;
        x = fmaxf(x, 0.0f);
        int xl = min((int)x, W - 1);
        int xh = min(xl + 1, W - 1);
        if (xl >= W - 1) x = (float)xl;
        s_lx[t] = x - (float)xl;
        s_wx[t] = v;
        s_xol[t] = xl * (IMGC / 8);
        s_xoh[t] = xh * (IMGC / 8);
    }
    __syncthreads();

    // ---- combined per-sample weights (valid * bilinear * 0.25) ----
    for (int idx = tid; idx < SAMP * SAMP; idx += BT) {
        int i = idx / SAMP;
        int j = idx - i * SAMP;
        float v  = s_wy[i] * s_wx[j] * 0.25f;
        float ly = s_ly[i], lx = s_lx[j];
        float hy = 1.0f - ly, hx = 1.0f - lx;
        float4 w;
        w.x = v * hy * hx;
        w.y = v * hy * lx;
        w.z = v * ly * hx;
        w.w = v * ly * lx;
        s_w[idx] = w;
    }
    __syncthreads();

    // ---- main: thread covers 8 channels (octet) for bins bg, bg+8, ... ----
    const int o  = tid & 15;
    const int bg = tid >> 4;
    const half8* fb = (const half8*)fp + (c0 >> 3) + o;

    for (int bin = bg; bin < NBIN; bin += 8) {
        int ph = bin / OUTP;
        int pw = bin - ph * OUTP;
        float acc[8];
        #pragma unroll
        for (int k = 0; k < 8; ++k) acc[k] = 0.0f;
        #pragma unroll
        for (int sy = 0; sy < 2; ++sy) {
            #pragma unroll
            for (int sx = 0; sx < 2; ++sx) {
                int i = 2 * ph + sy;
                int j = 2 * pw + sx;
                float4 w = s_w[i * SAMP + j];
                int yol = s_yol[i], yoh = s_yoh[i];
                int xol = s_xol[j], xoh = s_xoh[j];
                half8 v1 = fb[yol + xol];
                half8 v2 = fb[yol + xoh];
                half8 v3 = fb[yoh + xol];
                half8 v4 = fb[yoh + xoh];
                #pragma unroll
                for (int k = 0; k < 8; ++k) {
                    acc[k] += w.x * (float)v1[k] + w.y * (float)v2[k]
                            + w.z * (float)v3[k] + w.w * (float)v4[k];
                }
            }
        }
        float* tp = &tile[bin * TLD + 8 * o];
        *(float4*)(tp + 0) = make_float4(acc[0], acc[1], acc[2], acc[3]);
        *(float4*)(tp + 4) = make_float4(acc[4], acc[5], acc[6], acc[7]);
    }
    __syncthreads();

    // ---- coalesced store: out[n, c0..c0+127, 0..48] contiguous ----
    const int outbase = n * (IMGC * NBIN) + c0 * NBIN;
    for (int t = tid; t < BT * NBIN; t += BT) {
        int cl = t / NBIN;
        int bb = t - cl * NBIN;
        out[outbase + t] = tile[bb * TLD + cl];
    }
}

// ---------------------------------------------------------------------------
// Fallback: direct [B,C,H,W] fp32 layout (used only if ws too small)
// ---------------------------------------------------------------------------
__global__ __launch_bounds__(BT) void roialign_direct_kernel(
    const float* __restrict__ f0, const float* __restrict__ f1,
    const float* __restrict__ f2, const float* __restrict__ f3,
    const float* __restrict__ boxes, float* __restrict__ out)
{
    __shared__ float s_ly[SAMP], s_wy[SAMP], s_lx[SAMP], s_wx[SAMP];
    __shared__ int   s_yol[SAMP], s_yoh[SAMP], s_xol[SAMP], s_xoh[SAMP];
    __shared__ float tile[NBIN * (BT + 1)];

    const int tid = threadIdx.x;
    const int blk = blockIdx.x;
    const int n   = blk >> 1;
    const int c0  = (blk & 1) * BT;
    const int b   = n >> 8;

    const float x1 = boxes[n * 4 + 0];
    const float y1 = boxes[n * 4 + 1];
    const float x2 = boxes[n * 4 + 2];
    const float y2 = boxes[n * 4 + 3];

    float s = sqrtf(fmaxf((x2 - x1) * (y2 - y1), 1e-12f));
    float lf = floorf(4.0f + log2f(s / 224.0f) + 1e-6f);
    int lvl = (int)fminf(fmaxf(lf, 2.0f), 5.0f) - 2;

    const int   Htab[4]  = {200, 100, 50, 25};
    const float sctab[4] = {0.25f, 0.125f, 0.0625f, 0.03125f};
    const int   H = Htab[lvl];
    const int   W = H;
    const float scale = sctab[lvl];
    const float* fp = (lvl == 0) ? f0 : (lvl == 1) ? f1 : (lvl == 2) ? f2 : f3;

    const float x1s = x1 * scale, y1s = y1 * scale;
    const float roi_w = fmaxf(x2 * scale - x1s, 1.0f);
    const float roi_h = fmaxf(y2 * scale - y1s, 1.0f);
    const float bin_w = roi_w * (1.0f / OUTP);
    const float bin_h = roi_h * (1.0f / OUTP);

    if (tid < SAMP) {
        int t = tid;
        float off = (float)(t >> 1) + 0.25f + 0.5f * (float)(t & 1);
        float y = y1s + off * bin_h;
        float v = (y > -1.0f && y < (float)H) ? 1.0f : 0.0f;
        y = fmaxf(y, 0.0f);
        int yl = min((int)y, H - 1);
        int yh = min(yl + 1, H - 1);
        if (yl >= H - 1) y = (float)yl;
        s_ly[t] = y - (float)yl;
        s_wy[t] = v;
        s_yol[t] = yl * W; s_yoh[t] = yh * W;
    } else if (tid >= 64 && tid < 64 + SAMP) {
        int t = tid - 64;
        float off = (float)(t >> 1) + 0.25f + 0.5f * (float)(t & 1);
        float x = x1s + off * bin_w;
        float v = (x > -1.0f && x < (float)W) ? 1.0f : 0.0f;
        x = fmaxf(x, 0.0f);
        int xl = min((int)x, W - 1);
        int xh = min(xl + 1, W - 1);
        if (xl >= W - 1) x = (float)xl;
        s_lx[t] = x - (float)xl;
        s_wx[t] = v;
        s_xol[t] = xl; s_xoh[t] = xh;
    }
    __syncthreads();

    const int c  = c0 + tid;
    const int tb = (b * IMGC + c) * (H * W);

    for (int bin = 0; bin < NBIN; ++bin) {
        int ph = bin / OUTP;
        int pw = bin - ph * OUTP;
        float acc = 0.0f;
        #pragma unroll
        for (int sy = 0; sy < 2; ++sy) {
            #pragma unroll
            for (int sx = 0; sx < 2; ++sx) {
                int i = 2 * ph + sy;
                int j = 2 * pw + sx;
                float ly = s_ly[i], lx = s_lx[j];
                float hy = 1.0f - ly, hx = 1.0f - lx;
                float wm = s_wy[i] * s_wx[j];
                float v1 = fp[tb + s_yol[i] + s_xol[j]];
                float v2 = fp[tb + s_yol[i] + s_xoh[j]];
                float v3 = fp[tb + s_yoh[i] + s_xol[j]];
                float v4 = fp[tb + s_yoh[i] + s_xoh[j]];
                acc += wm * (hy * (hx * v1 + lx * v2) + ly * (hx * v3 + lx * v4));
            }
        }
        tile[bin * (BT + 1) + tid] = acc * 0.25f;
    }
    __syncthreads();

    const int outbase = n * (IMGC * NBIN) + c0 * NBIN;
    for (int t = tid; t < BT * NBIN; t += BT) {
        int cl = t / NBIN;
        int bb = t - cl * NBIN;
        out[outbase + t] = tile[bb * (BT + 1) + cl];
    }
}

extern "C" void kernel_launch(void* const* d_in, const int* in_sizes, int n_in,
                              void* d_out, int out_size, void* d_ws, size_t ws_size,
                              hipStream_t stream) {
    const float* f0    = (const float*)d_in[0];
    const float* f1    = (const float*)d_in[1];
    const float* f2    = (const float*)d_in[2];
    const float* f3    = (const float*)d_in[3];
    const float* boxes = (const float*)d_in[4];
    float* out = (float*)d_out;

    const bool use_cl = ws_size >= (size_t)WS_TOT * sizeof(_Float16);

    if (use_cl) {
        _Float16* w = (_Float16*)d_ws;
        transpose_cl_h3_kernel<<<3328, 256, 0, stream>>>(f0, f1, f2, f3, w);
        roialign_h_kernel<<<1024, BT, 0, stream>>>(w, boxes, out);
    } else {
        roialign_direct_kernel<<<1024, BT, 0, stream>>>(f0, f1, f2, f3, boxes, out);
    }
}